// Round 1
// baseline (1125.853 us; speedup 1.0000x reference)
//
#include <hip/hip_runtime.h>
#include <stdint.h>
#include <stddef.h>

// out[16384,4096] = x[16384,4096] @ W[4096,4096] + bias
// W = (kron(L0,R0) + kron(L1,R1) + kron(L2,R2)) / 3
// GEMM: 256x256 tile, BK=64, 8 waves, 16x16x32 bf16 MFMA, 8-phase schedule
// with counted vmcnt(6) (m201-style template), XOR-swizzled LDS, XCD swizzle.

#define M_TOT 16384
#define N_TOT 4096
#define K_TOT 4096

#define BM 256
#define BN 256
#define BK 64
#define NTILES (K_TOT / BK)   // 64
#define NITER  (NTILES / 2)   // 32

typedef __attribute__((ext_vector_type(8)))  short          short8;
typedef __attribute__((ext_vector_type(4)))  float          f32x4;
typedef __attribute__((ext_vector_type(8)))  unsigned short ushort8;

__device__ __forceinline__ unsigned short f2bf(float f) {
    unsigned int u = __float_as_uint(f);
    u += 0x7FFFu + ((u >> 16) & 1u);   // RNE
    return (unsigned short)(u >> 16);
}

// ---------------------------------------------------------------------------
// Kernel 1: W^T[n, k] (bf16) from Kronecker factors.
// ---------------------------------------------------------------------------
__global__ void build_wt(const float* __restrict__ L0, const float* __restrict__ R0,
                         const float* __restrict__ L1, const float* __restrict__ R1,
                         const float* __restrict__ L2, const float* __restrict__ R2,
                         unsigned short* __restrict__ Wt) {
    int idx = blockIdx.x * 256 + threadIdx.x;       // n*4096 + k, k contiguous
    int k = idx & (K_TOT - 1);
    int n = idx >> 12;
    float w0 = L0[(k >> 6) * 64 + (n >> 6)]  * R0[(k & 63)  * 64  + (n & 63)];
    float w1 = L1[(k >> 7) * 32 + (n >> 7)]  * R1[(k & 127) * 128 + (n & 127)];
    float w2 = L2[(k >> 5) * 128 + (n >> 5)] * R2[(k & 31)  * 32  + (n & 31)];
    Wt[idx] = f2bf((w0 + w1 + w2) * (1.0f / 3.0f));
}

// ---------------------------------------------------------------------------
// Kernel 2: x fp32 -> bf16 (8 elems / thread)
// ---------------------------------------------------------------------------
__global__ void convert_x(const float* __restrict__ x, unsigned short* __restrict__ xb) {
    int idx = blockIdx.x * 256 + threadIdx.x;
    const f32x4* xv = (const f32x4*)x;
    f32x4 a = xv[idx * 2 + 0];
    f32x4 b = xv[idx * 2 + 1];
    ushort8 o;
    o[0] = f2bf(a[0]); o[1] = f2bf(a[1]); o[2] = f2bf(a[2]); o[3] = f2bf(a[3]);
    o[4] = f2bf(b[0]); o[5] = f2bf(b[1]); o[6] = f2bf(b[2]); o[7] = f2bf(b[3]);
    ((ushort8*)xb)[idx] = o;
}

// ---------------------------------------------------------------------------
// Kernel 3: GEMM  C = A(bf16)[M,K] * B^T(bf16)[N,K] + bias, C fp32 [M,N]
//
// LDS layout (bf16 elems):
//   As[buf(2)][region(4)][64 rows][64 k]   region = wm*2 + qm (tile rows wm*128+qm*64)
//   Bs[buf(2)][region(8)][32 rows][64 k]   region = wn*2 + qn (tile cols wn*64+qn*32)
// Staged half-tile h of A = regions {h, 2+h}; of B = regions {h,2+h,4+h,6+h}.
// 16B chunks XOR-swizzled on the GLOBAL side: LDS[row][slot] holds global
// chunk slot^(row&7); ds_read uses chunk (ks*4+l4)^(row&7). Conflict-floor.
//
// Per-iter schedule (2 K-tiles T=2it,T+1; G0 phases P1-4 on buf0, G1 P5-8 buf1):
//   P1: read A0,B0   stage A-h1(T+1)->b1
//   P2: read B1      stage A-h0(T+2)->b0
//   P3: read A1      stage B-h0(T+2)->b0
//   P4: (regs only)  stage B-h1(T+2)->b0   vmcnt(6)
//   P5: read A0,B0   stage A-h1(T+2)->b0
//   P6: read B1      stage A-h0(T+3)->b1
//   P7: read A1      stage B-h0(T+3)->b1
//   P8: (regs only)  stage B-h1(T+3)->b1   vmcnt(6)
// Every staged region's last ds_read is >=1 barrier-pair earlier (race-free);
// every read is landing-guaranteed by the previous vmcnt(6)+barrier.
// ---------------------------------------------------------------------------
__device__ __forceinline__ void gload16(const unsigned short* g, unsigned short* l) {
    __builtin_amdgcn_global_load_lds(
        (const __attribute__((address_space(1))) void*)g,
        (__attribute__((address_space(3))) void*)l,
        16, 0, 0);
}

#define SBAR() do { __builtin_amdgcn_sched_barrier(0); \
                    __builtin_amdgcn_s_barrier(); \
                    __builtin_amdgcn_sched_barrier(0); } while (0)
#define LGKM0() do { asm volatile("s_waitcnt lgkmcnt(0)" ::: "memory"); \
                     __builtin_amdgcn_sched_barrier(0); } while (0)

__launch_bounds__(512, 2)
__global__ void gemm_bias(const unsigned short* __restrict__ A,   // [M,K] bf16
                          const unsigned short* __restrict__ B,   // [N,K] bf16 (=W^T)
                          const float* __restrict__ bias,
                          float* __restrict__ C) {
    __shared__ __align__(16) unsigned short As[32768];   // 64 KB
    __shared__ __align__(16) unsigned short Bs[32768];   // 64 KB

    const int tid  = threadIdx.x;
    const int wid  = tid >> 6;       // wave 0..7
    const int lane = tid & 63;

    // XCD-aware swizzle: xcd owns 2 n-blocks (512 cols x 4096 K x 2B = 4MB = L2)
    const int id    = blockIdx.x;
    const int xcd   = id & 7;
    const int local = id >> 3;                    // 0..127
    const int n0 = (xcd * 2 + (local & 1)) * BN;
    const int m0 = (local >> 1) * BM;

    const int wm = wid >> 2;         // 0..1 -> rows wm*128..+128
    const int wn = wid & 3;          // 0..3 -> cols wn*64..+64

    // ---- staging addressing (per-thread, 2 gload16 per half-tile) ----
    const int srow   = lane >> 3;            // 0..7
    const int schunk = (lane & 7) ^ srow;    // swizzled global 16B-chunk

    int aLo[2], bLo[2], aGo[2], bGo[2];      // elem offsets
#pragma unroll
    for (int s = 0; s < 2; ++s) {
        const int g = wid * 2 + s;                           // 0..15
        aLo[s] = (g >> 3) * 8192 + (g & 7) * 512;            // + h*4096 + buf*16384
        aGo[s] = (m0 + (g >> 3) * 128 + (g & 7) * 8 + srow) * K_TOT + schunk * 8;
        const int wng = g >> 2, sub = g & 3;
        bLo[s] = wng * 4096 + sub * 512;                     // + h*2048 + buf*16384
        bGo[s] = (n0 + wng * 64 + sub * 8 + srow) * K_TOT + schunk * 8;
    }

    // ---- fragment read addressing (16x16x32: row=lane&15, k-octet=lane>>4) ----
    const int ln15 = lane & 15;
    const int l4   = lane >> 4;                       // 0..3
    const int ck0  = ((0 * 4 + l4) ^ (ln15 & 7)) * 8; // ks=0 swizzled chunk (elems)
    const int ck1  = ((1 * 4 + l4) ^ (ln15 & 7)) * 8; // ks=1
    const int aRb  = wm * 8192 + ln15 * 64;           // + qm*4096 + r*1024
    const int bRb  = wn * 4096 + ln15 * 64;           // + qn*2048 + j*1024

    f32x4 acc[8][4];
#pragma unroll
    for (int i = 0; i < 8; ++i)
#pragma unroll
        for (int j = 0; j < 4; ++j)
            acc[i][j] = (f32x4)(0.0f);

    short8 afr[4][2];        // [mrep r][ks]
    short8 bfr[2][2][2];     // [qn][nrep j][ks]

#define STAGE_A(t, h, bf) do { \
    gload16(A + (size_t)(aGo[0] + (h) * 64 * K_TOT + (t) * 64), &As[(bf) * 16384 + (h) * 4096 + aLo[0]]); \
    gload16(A + (size_t)(aGo[1] + (h) * 64 * K_TOT + (t) * 64), &As[(bf) * 16384 + (h) * 4096 + aLo[1]]); \
} while (0)
#define STAGE_B(t, h, bf) do { \
    gload16(B + (size_t)(bGo[0] + (h) * 32 * K_TOT + (t) * 64), &Bs[(bf) * 16384 + (h) * 2048 + bLo[0]]); \
    gload16(B + (size_t)(bGo[1] + (h) * 32 * K_TOT + (t) * 64), &Bs[(bf) * 16384 + (h) * 2048 + bLo[1]]); \
} while (0)
#define LDA(bf, qm) do { \
    _Pragma("unroll") for (int r = 0; r < 4; ++r) { \
        afr[r][0] = *(const short8*)&As[(bf) * 16384 + (qm) * 4096 + aRb + r * 1024 + ck0]; \
        afr[r][1] = *(const short8*)&As[(bf) * 16384 + (qm) * 4096 + aRb + r * 1024 + ck1]; \
    } } while (0)
#define LDB(bf, qn) do { \
    _Pragma("unroll") for (int j = 0; j < 2; ++j) { \
        bfr[qn][j][0] = *(const short8*)&Bs[(bf) * 16384 + (qn) * 2048 + bRb + j * 1024 + ck0]; \
        bfr[qn][j][1] = *(const short8*)&Bs[(bf) * 16384 + (qn) * 2048 + bRb + j * 1024 + ck1]; \
    } } while (0)
#define MFMA_Q(qm, qn) do { \
    _Pragma("unroll") for (int ks = 0; ks < 2; ++ks) \
    _Pragma("unroll") for (int r = 0; r < 4; ++r) \
    _Pragma("unroll") for (int j = 0; j < 2; ++j) \
        acc[(qm) * 4 + r][(qn) * 2 + j] = __builtin_amdgcn_mfma_f32_16x16x32_bf16( \
            afr[r][ks], bfr[qn][j][ks], acc[(qm) * 4 + r][(qn) * 2 + j], 0, 0, 0); \
} while (0)

    // ---- prologue: tile0 full (4 half-tiles) + tile1 {A-h0,B-h0,B-h1} ----
    STAGE_A(0, 0, 0); STAGE_A(0, 1, 0);
    STAGE_B(0, 0, 0); STAGE_B(0, 1, 0);
    STAGE_A(1, 0, 1); STAGE_B(1, 0, 1); STAGE_B(1, 1, 1);
    asm volatile("s_waitcnt vmcnt(6)" ::: "memory");   // tile0 landed; 3 halves in flight
    SBAR();

    for (int it = 0; it < NITER; ++it) {
        const int T = 2 * it;
        const bool st = (it < NITER - 1);

        // ================= G0: tile T from buf0 =================
        // P1: quadrant (0,0)
        LDA(0, 0); LDB(0, 0);
        STAGE_A(T + 1, 1, 1);
        SBAR(); LGKM0();
        __builtin_amdgcn_s_setprio(1); MFMA_Q(0, 0); __builtin_amdgcn_s_setprio(0);
        SBAR();
        // P2: quadrant (0,1)
        LDB(0, 1);
        if (st) STAGE_A(T + 2, 0, 0);
        SBAR(); LGKM0();
        __builtin_amdgcn_s_setprio(1); MFMA_Q(0, 1); __builtin_amdgcn_s_setprio(0);
        SBAR();
        // P3: quadrant (1,0)
        LDA(0, 1);
        if (st) STAGE_B(T + 2, 0, 0);
        SBAR(); LGKM0();
        __builtin_amdgcn_s_setprio(1); MFMA_Q(1, 0); __builtin_amdgcn_s_setprio(0);
        SBAR();
        // P4: quadrant (1,1) — regs only; counted vmcnt
        if (st) STAGE_B(T + 2, 1, 0);
        SBAR();
        __builtin_amdgcn_s_setprio(1); MFMA_Q(1, 1); __builtin_amdgcn_s_setprio(0);
        if (st) asm volatile("s_waitcnt vmcnt(6)" ::: "memory");
        else    asm volatile("s_waitcnt vmcnt(0)" ::: "memory");   // tail drain
        __builtin_amdgcn_sched_barrier(0);
        SBAR();

        // ================= G1: tile T+1 from buf1 =================
        // P5: quadrant (0,0)
        LDA(1, 0); LDB(1, 0);
        if (st) STAGE_A(T + 2, 1, 0);
        SBAR(); LGKM0();
        __builtin_amdgcn_s_setprio(1); MFMA_Q(0, 0); __builtin_amdgcn_s_setprio(0);
        SBAR();
        // P6: quadrant (0,1)
        LDB(1, 1);
        if (st) STAGE_A(T + 3, 0, 1);
        SBAR(); LGKM0();
        __builtin_amdgcn_s_setprio(1); MFMA_Q(0, 1); __builtin_amdgcn_s_setprio(0);
        SBAR();
        // P7: quadrant (1,0)
        LDA(1, 1);
        if (st) STAGE_B(T + 3, 0, 1);
        SBAR(); LGKM0();
        __builtin_amdgcn_s_setprio(1); MFMA_Q(1, 0); __builtin_amdgcn_s_setprio(0);
        SBAR();
        // P8: quadrant (1,1) — regs only; counted vmcnt
        if (st) STAGE_B(T + 3, 1, 1);
        SBAR();
        __builtin_amdgcn_s_setprio(1); MFMA_Q(1, 1); __builtin_amdgcn_s_setprio(0);
        asm volatile("s_waitcnt vmcnt(6)" ::: "memory");
        __builtin_amdgcn_sched_barrier(0);
        SBAR();
    }

    // ---- epilogue: C/D layout col = lane&15, row = (lane>>4)*4 + reg ----
#pragma unroll
    for (int qn = 0; qn < 2; ++qn)
#pragma unroll
    for (int j = 0; j < 2; ++j) {
        const int col = n0 + wn * 64 + qn * 32 + j * 16 + ln15;
        const float bv = bias[col];
#pragma unroll
        for (int qm = 0; qm < 2; ++qm)
#pragma unroll
        for (int r = 0; r < 4; ++r) {
            const f32x4 v = acc[qm * 4 + r][qn * 2 + j];
            const size_t rb = (size_t)(m0 + wm * 128 + qm * 64 + r * 16 + l4 * 4) * N_TOT + col;
            C[rb]             = v[0] + bv;
            C[rb + N_TOT]     = v[1] + bv;
            C[rb + 2 * N_TOT] = v[2] + bv;
            C[rb + 3 * N_TOT] = v[3] + bv;
        }
    }
#undef STAGE_A
#undef STAGE_B
#undef LDA
#undef LDB
#undef MFMA_Q
}

// ---------------------------------------------------------------------------
extern "C" void kernel_launch(void* const* d_in, const int* in_sizes, int n_in,
                              void* d_out, int out_size, void* d_ws, size_t ws_size,
                              hipStream_t stream) {
    const float* x    = (const float*)d_in[0];
    const float* L0   = (const float*)d_in[1];
    const float* R0   = (const float*)d_in[2];
    const float* L1   = (const float*)d_in[3];
    const float* R1   = (const float*)d_in[4];
    const float* L2   = (const float*)d_in[5];
    const float* R2   = (const float*)d_in[6];
    const float* bias = (const float*)d_in[7];
    float* out = (float*)d_out;

    unsigned short* xb = (unsigned short*)d_ws;                                  // 134 MB
    unsigned short* wt = (unsigned short*)((char*)d_ws + (size_t)134217728);     // 33.5 MB

    build_wt<<<dim3((N_TOT * K_TOT) / 256), dim3(256), 0, stream>>>(L0, R0, L1, R1, L2, R2, wt);
    convert_x<<<dim3((M_TOT * K_TOT) / (256 * 8)), dim3(256), 0, stream>>>(x, xb);
    gemm_bias<<<dim3((M_TOT / BM) * (N_TOT / BN)), dim3(512), 0, stream>>>(xb, wt, bias, out);
}

// Round 2
// 1113.779 us; speedup vs baseline: 1.0108x; 1.0108x over previous
//
#include <hip/hip_runtime.h>
#include <stdint.h>
#include <stddef.h>

// out[16384,4096] = x[16384,4096] @ W[4096,4096] + bias
// W = (kron(L0,R0) + kron(L1,R1) + kron(L2,R2)) / 3
// GEMM: 256x256 tile, BK=64, 8 waves, 16x16x32 bf16 MFMA, 8-phase schedule
// with counted vmcnt(6), minimal sched_barrier pinning, XOR LDS swizzle,
// XCD-aware block swizzle.

#define M_TOT 16384
#define N_TOT 4096
#define K_TOT 4096

#define BM 256
#define BN 256
#define BK 64
#define NTILES (K_TOT / BK)   // 64
#define NITER  (NTILES / 2)   // 32

typedef __attribute__((ext_vector_type(8)))  short          short8;
typedef __attribute__((ext_vector_type(4)))  float          f32x4;
typedef __attribute__((ext_vector_type(8)))  unsigned short ushort8;

__device__ __forceinline__ unsigned short f2bf(float f) {
    unsigned int u = __float_as_uint(f);
    u += 0x7FFFu + ((u >> 16) & 1u);   // RNE
    return (unsigned short)(u >> 16);
}

// ---------------------------------------------------------------------------
// Kernel 1: W^T[n, k] (bf16) from Kronecker factors.
// ---------------------------------------------------------------------------
__global__ void build_wt(const float* __restrict__ L0, const float* __restrict__ R0,
                         const float* __restrict__ L1, const float* __restrict__ R1,
                         const float* __restrict__ L2, const float* __restrict__ R2,
                         unsigned short* __restrict__ Wt) {
    int idx = blockIdx.x * 256 + threadIdx.x;       // n*4096 + k, k contiguous
    int k = idx & (K_TOT - 1);
    int n = idx >> 12;
    float w0 = L0[(k >> 6) * 64 + (n >> 6)]  * R0[(k & 63)  * 64  + (n & 63)];
    float w1 = L1[(k >> 7) * 32 + (n >> 7)]  * R1[(k & 127) * 128 + (n & 127)];
    float w2 = L2[(k >> 5) * 128 + (n >> 5)] * R2[(k & 31)  * 32  + (n & 31)];
    Wt[idx] = f2bf((w0 + w1 + w2) * (1.0f / 3.0f));
}

// ---------------------------------------------------------------------------
// Kernel 2: x fp32 -> bf16 (8 elems / thread)
// ---------------------------------------------------------------------------
__global__ void convert_x(const float* __restrict__ x, unsigned short* __restrict__ xb) {
    int idx = blockIdx.x * 256 + threadIdx.x;
    const f32x4* xv = (const f32x4*)x;
    f32x4 a = xv[idx * 2 + 0];
    f32x4 b = xv[idx * 2 + 1];
    ushort8 o;
    o[0] = f2bf(a[0]); o[1] = f2bf(a[1]); o[2] = f2bf(a[2]); o[3] = f2bf(a[3]);
    o[4] = f2bf(b[0]); o[5] = f2bf(b[1]); o[6] = f2bf(b[2]); o[7] = f2bf(b[3]);
    ((ushort8*)xb)[idx] = o;
}

// ---------------------------------------------------------------------------
// Kernel 3: GEMM  C = A(bf16)[M,K] * B^T(bf16)[N,K] + bias, C fp32 [M,N]
//
// LDS layout (bf16 elems):
//   As[buf(2)][qm-region(2)x wm(2)][64 rows][64 k]; Bs[buf(2)][8 x 32 rows][64 k]
// A half-tile h = qm regions h; B half-tile h = qn regions h.
// 16B chunks XOR-swizzled on the GLOBAL side: LDS[row][slot] holds global
// chunk slot^(row&7); ds_read uses chunk (ks*4+l4)^(row&7). Conflict-free (R1 PMC: 0).
//
// Pin discipline (race-freedom, minimal):
//  - sched_barrier(0) before BAR_b of P1/P3/P5/P7: bounds phase reads+stages so
//    no ds_read of region R survives past the barrier after which R is restaged.
//  - sched_barrier(0) around vmcnt(6) at P4/P8 + after the following barrier:
//    buf-switch reads can't hoist above the cross-wave landing guarantee.
//  - All lgkm waits are compiler-inserted (reads are IR-visible loads).
// ---------------------------------------------------------------------------
__device__ __forceinline__ void gload16(const unsigned short* g, unsigned short* l) {
    __builtin_amdgcn_global_load_lds(
        (const __attribute__((address_space(1))) void*)g,
        (__attribute__((address_space(3))) void*)l,
        16, 0, 0);
}

#define PIN() __builtin_amdgcn_sched_barrier(0)
#define BAR() __builtin_amdgcn_s_barrier()
#define PRIO1() __builtin_amdgcn_s_setprio(1)
#define PRIO0() __builtin_amdgcn_s_setprio(0)

__launch_bounds__(512, 2)
__global__ void gemm_bias(const unsigned short* __restrict__ A,   // [M,K] bf16
                          const unsigned short* __restrict__ B,   // [N,K] bf16 (=W^T)
                          const float* __restrict__ bias,
                          float* __restrict__ C) {
    __shared__ __align__(16) unsigned short As[32768];   // 64 KB
    __shared__ __align__(16) unsigned short Bs[32768];   // 64 KB

    const int tid  = threadIdx.x;
    const int wid  = tid >> 6;       // wave 0..7
    const int lane = tid & 63;

    // XCD-aware swizzle: xcd owns 2 n-blocks (512 cols x 4096 K x 2B = 4MB = L2)
    const int id    = blockIdx.x;
    const int xcd   = id & 7;
    const int local = id >> 3;                    // 0..127
    const int n0 = (xcd * 2 + (local & 1)) * BN;
    const int m0 = (local >> 1) * BM;

    const int wm = wid >> 2;         // 0..1 -> rows wm*128..+128
    const int wn = wid & 3;          // 0..3 -> cols wn*64..+64

    // ---- staging addressing (per-thread, 2 gload16 per half-tile) ----
    const int srow   = lane >> 3;            // 0..7
    const int schunk = (lane & 7) ^ srow;    // swizzled global 16B-chunk

    int aLo[2], bLo[2], aGo[2], bGo[2];      // elem offsets
#pragma unroll
    for (int s = 0; s < 2; ++s) {
        const int g = wid * 2 + s;                           // 0..15
        aLo[s] = (g >> 3) * 8192 + (g & 7) * 512;            // + h*4096 + buf*16384
        aGo[s] = (m0 + (g >> 3) * 128 + (g & 7) * 8 + srow) * K_TOT + schunk * 8;
        const int wng = g >> 2, sub = g & 3;
        bLo[s] = wng * 4096 + sub * 512;                     // + h*2048 + buf*16384
        bGo[s] = (n0 + wng * 64 + sub * 8 + srow) * K_TOT + schunk * 8;
    }

    // ---- fragment read addressing (16x16x32: row=lane&15, k-octet=lane>>4) ----
    const int ln15 = lane & 15;
    const int l4   = lane >> 4;                       // 0..3
    const int ck0  = ((0 * 4 + l4) ^ (ln15 & 7)) * 8; // ks=0 swizzled chunk (elems)
    const int ck1  = ((1 * 4 + l4) ^ (ln15 & 7)) * 8; // ks=1
    const int aRb  = wm * 8192 + ln15 * 64;           // + qm*4096 + r*1024
    const int bRb  = wn * 4096 + ln15 * 64;           // + qn*2048 + j*1024

    f32x4 acc[8][4];
#pragma unroll
    for (int i = 0; i < 8; ++i)
#pragma unroll
        for (int j = 0; j < 4; ++j)
            acc[i][j] = (f32x4)(0.0f);

    short8 afr[4][2];        // [mrep r][ks]
    short8 bfr[2][2][2];     // [qn][nrep j][ks]

#define STAGE_A(t, h, bf) do { \
    gload16(A + (size_t)(aGo[0] + (h) * 64 * K_TOT + (t) * 64), &As[(bf) * 16384 + (h) * 4096 + aLo[0]]); \
    gload16(A + (size_t)(aGo[1] + (h) * 64 * K_TOT + (t) * 64), &As[(bf) * 16384 + (h) * 4096 + aLo[1]]); \
} while (0)
#define STAGE_B(t, h, bf) do { \
    gload16(B + (size_t)(bGo[0] + (h) * 32 * K_TOT + (t) * 64), &Bs[(bf) * 16384 + (h) * 2048 + bLo[0]]); \
    gload16(B + (size_t)(bGo[1] + (h) * 32 * K_TOT + (t) * 64), &Bs[(bf) * 16384 + (h) * 2048 + bLo[1]]); \
} while (0)
#define LDA(bf, qm) do { \
    _Pragma("unroll") for (int r = 0; r < 4; ++r) { \
        afr[r][0] = *(const short8*)&As[(bf) * 16384 + (qm) * 4096 + aRb + r * 1024 + ck0]; \
        afr[r][1] = *(const short8*)&As[(bf) * 16384 + (qm) * 4096 + aRb + r * 1024 + ck1]; \
    } } while (0)
#define LDB(bf, qn) do { \
    _Pragma("unroll") for (int j = 0; j < 2; ++j) { \
        bfr[qn][j][0] = *(const short8*)&Bs[(bf) * 16384 + (qn) * 2048 + bRb + j * 1024 + ck0]; \
        bfr[qn][j][1] = *(const short8*)&Bs[(bf) * 16384 + (qn) * 2048 + bRb + j * 1024 + ck1]; \
    } } while (0)
#define MFMA_Q(qm, qn) do { \
    _Pragma("unroll") for (int ks = 0; ks < 2; ++ks) \
    _Pragma("unroll") for (int r = 0; r < 4; ++r) \
    _Pragma("unroll") for (int j = 0; j < 2; ++j) \
        acc[(qm) * 4 + r][(qn) * 2 + j] = __builtin_amdgcn_mfma_f32_16x16x32_bf16( \
            afr[r][ks], bfr[qn][j][ks], acc[(qm) * 4 + r][(qn) * 2 + j], 0, 0, 0); \
} while (0)

    // ---- prologue: tile0 full (4 half-tiles) + tile1 {A-h0,B-h0,B-h1} ----
    STAGE_A(0, 0, 0); STAGE_A(0, 1, 0);
    STAGE_B(0, 0, 0); STAGE_B(0, 1, 0);
    STAGE_A(1, 0, 1); STAGE_B(1, 0, 1); STAGE_B(1, 1, 1);
    PIN(); asm volatile("s_waitcnt vmcnt(6)"); PIN();   // tile0 landed; 3 halves in flight
    BAR(); PIN();

    for (int it = 0; it < NITER - 1; ++it) {
        const int T = 2 * it;

        // ================= G0: tile T from buf0 =================
        // P1
        LDA(0, 0); LDB(0, 0);
        STAGE_A(T + 1, 1, 1);
        BAR();
        PRIO1(); MFMA_Q(0, 0); PRIO0();
        PIN(); BAR();
        // P2
        LDB(0, 1);
        STAGE_A(T + 2, 0, 0);
        BAR();
        PRIO1(); MFMA_Q(0, 1); PRIO0();
        BAR();
        // P3
        LDA(0, 1);
        STAGE_B(T + 2, 0, 0);
        BAR();
        PRIO1(); MFMA_Q(1, 0); PRIO0();
        PIN(); BAR();
        // P4 — counted vmcnt once per K-tile
        STAGE_B(T + 2, 1, 0);
        BAR();
        PRIO1(); MFMA_Q(1, 1); PRIO0();
        PIN(); asm volatile("s_waitcnt vmcnt(6)"); PIN();
        BAR(); PIN();

        // ================= G1: tile T+1 from buf1 =================
        // P5
        LDA(1, 0); LDB(1, 0);
        STAGE_A(T + 2, 1, 0);
        BAR();
        PRIO1(); MFMA_Q(0, 0); PRIO0();
        PIN(); BAR();
        // P6
        LDB(1, 1);
        STAGE_A(T + 3, 0, 1);
        BAR();
        PRIO1(); MFMA_Q(0, 1); PRIO0();
        BAR();
        // P7
        LDA(1, 1);
        STAGE_B(T + 3, 0, 1);
        BAR();
        PRIO1(); MFMA_Q(1, 0); PRIO0();
        PIN(); BAR();
        // P8 — counted vmcnt once per K-tile
        STAGE_B(T + 3, 1, 1);
        BAR();
        PRIO1(); MFMA_Q(1, 1); PRIO0();
        PIN(); asm volatile("s_waitcnt vmcnt(6)"); PIN();
        BAR(); PIN();
    }

    // ================= peeled last iteration: tiles 62 (buf0), 63 (buf1) ====
    {
        // P1 — last stage of the kernel (A-h1 of tile 63 -> buf1)
        LDA(0, 0); LDB(0, 0);
        STAGE_A(63, 1, 1);
        BAR();
        PRIO1(); MFMA_Q(0, 0); PRIO0();
        PIN(); BAR();
        // P2
        LDB(0, 1);
        BAR();
        PRIO1(); MFMA_Q(0, 1); PRIO0();
        BAR();
        // P3
        LDA(0, 1);
        BAR();
        PRIO1(); MFMA_Q(1, 0); PRIO0();
        BAR();
        // P4 — drain all stages, then buf1 is fully valid for every wave
        PRIO1(); MFMA_Q(1, 1); PRIO0();
        PIN(); asm volatile("s_waitcnt vmcnt(0)"); PIN();
        BAR(); PIN();
        // P5..P8 — no stages in flight: barrier-free drain at full ILP
        LDA(1, 0); LDB(1, 0);
        MFMA_Q(0, 0);
        LDB(1, 1);
        MFMA_Q(0, 1);
        LDA(1, 1);
        MFMA_Q(1, 0);
        MFMA_Q(1, 1);
    }

    // ---- epilogue: C/D layout col = lane&15, row = (lane>>4)*4 + reg ----
#pragma unroll
    for (int qn = 0; qn < 2; ++qn)
#pragma unroll
    for (int j = 0; j < 2; ++j) {
        const int col = n0 + wn * 64 + qn * 32 + j * 16 + ln15;
        const float bv = bias[col];
#pragma unroll
        for (int qm = 0; qm < 2; ++qm)
#pragma unroll
        for (int r = 0; r < 4; ++r) {
            const f32x4 v = acc[qm * 4 + r][qn * 2 + j];
            const size_t rb = (size_t)(m0 + wm * 128 + qm * 64 + r * 16 + l4 * 4) * N_TOT + col;
            C[rb]             = v[0] + bv;
            C[rb + N_TOT]     = v[1] + bv;
            C[rb + 2 * N_TOT] = v[2] + bv;
            C[rb + 3 * N_TOT] = v[3] + bv;
        }
    }
#undef STAGE_A
#undef STAGE_B
#undef LDA
#undef LDB
#undef MFMA_Q
}

// ---------------------------------------------------------------------------
extern "C" void kernel_launch(void* const* d_in, const int* in_sizes, int n_in,
                              void* d_out, int out_size, void* d_ws, size_t ws_size,
                              hipStream_t stream) {
    const float* x    = (const float*)d_in[0];
    const float* L0   = (const float*)d_in[1];
    const float* R0   = (const float*)d_in[2];
    const float* L1   = (const float*)d_in[3];
    const float* R1   = (const float*)d_in[4];
    const float* L2   = (const float*)d_in[5];
    const float* R2   = (const float*)d_in[6];
    const float* bias = (const float*)d_in[7];
    float* out = (float*)d_out;

    unsigned short* xb = (unsigned short*)d_ws;                                  // 134 MB
    unsigned short* wt = (unsigned short*)((char*)d_ws + (size_t)134217728);     // 33.5 MB

    build_wt<<<dim3((N_TOT * K_TOT) / 256), dim3(256), 0, stream>>>(L0, R0, L1, R1, L2, R2, wt);
    convert_x<<<dim3((M_TOT * K_TOT) / (256 * 8)), dim3(256), 0, stream>>>(x, xb);
    gemm_bias<<<dim3((M_TOT / BM) * (N_TOT / BN)), dim3(512), 0, stream>>>(xb, wt, bias, out);
}

// Round 3
// 824.107 us; speedup vs baseline: 1.3661x; 1.3515x over previous
//
#include <hip/hip_runtime.h>
#include <stdint.h>
#include <stddef.h>

// out[16384,4096] = x @ W + bias,  W = (kron(L0,R0)+kron(L1,R1)+kron(L2,R2))/3
//
// Kronecker identity (verified vs reference einsum 'ab,cd->acbd'):
//   i = iL*r + iR, j = jL*s + jR  =>  y_row[jL,jR] = (L^T · X · R)[jL,jR],
//   X = reshape(x_row, [p, r]).  All factors are square: q=p, s=r, p*r=4096.
// Per row per factor:  stepA: U[iL,jR] = sum_iR X[iL,iR]*R[iR,jR]   (K = iR, contiguous)
//                      stepB: out[jL,jR] += sum_iL Lt[jL,iL]*U[iL,jR] (K = iL, contiguous
//                             because U is stored [jR][iL] column-major in LDS)
// FLOP total 6.0e10 (9.2x less than dense GEMM); memory floor 268MB in + 268MB out.
//
// Layout: 256 blocks (1/CU) x 8 waves = 4 wave-pairs/block; a pair owns a row,
// waves split the jR (N) dimension in halves -> U is wave-private (no barrier
// between stepA and stepB). 3 __syncthreads per row (X-ready, pre-flush, post-flush).
//
// LDS per pair: X row 8KB bf16 (chunk-swizzled), 2x4KB U (per wave), 16.9KB fp32
// out accumulator (padded j + (j>>5) to spread banks). Total 133,120 B.

#define M_TOT 16384
#define N_TOT 4096

typedef __attribute__((ext_vector_type(4))) float f32x4;
typedef __attribute__((ext_vector_type(8))) short short8;

__device__ __forceinline__ unsigned int f2bf(float f) {
    unsigned int u = __float_as_uint(f);
    u += 0x7FFFu + ((u >> 16) & 1u);   // RNE
    return u >> 16;
}

#define PIN() __builtin_amdgcn_sched_barrier(0)

// ws layout (bf16 elems): Lt0@0[64x64] Rt0@4096[64x64] Lt1@8192[32x32]
// Rt1@9216[128x128] Lt2@25600[128x128] Rt2@41984[32x32]  (Lt = L^T/3, Rt = R^T)
#define LT0 0
#define RT0 4096
#define LT1 8192
#define RT1 9216
#define LT2 25600
#define RT2 41984

__global__ void prep(const float* __restrict__ L0, const float* __restrict__ R0,
                     const float* __restrict__ L1, const float* __restrict__ R1,
                     const float* __restrict__ L2, const float* __restrict__ R2,
                     unsigned short* __restrict__ F) {
    int idx = blockIdx.x * 256 + threadIdx.x;          // 43008 total
    float v; int a, b, o;
    if (idx < 4096)        { o = idx;         a = o >> 6; b = o & 63;  v = L0[b * 64 + a] * (1.0f/3.0f); }
    else if (idx < 8192)   { o = idx - 4096;  a = o >> 6; b = o & 63;  v = R0[b * 64 + a]; }
    else if (idx < 9216)   { o = idx - 8192;  a = o >> 5; b = o & 31;  v = L1[b * 32 + a] * (1.0f/3.0f); }
    else if (idx < 25600)  { o = idx - 9216;  a = o >> 7; b = o & 127; v = R1[b * 128 + a]; }
    else if (idx < 41984)  { o = idx - 25600; a = o >> 7; b = o & 127; v = L2[b * 128 + a] * (1.0f/3.0f); }
    else                   { o = idx - 41984; a = o >> 5; b = o & 31;  v = R2[b * 32 + a]; }
    F[idx] = (unsigned short)f2bf(v);
}

// Chunk swizzle (16B chunks): slot = T ^ ((T>>3)&7). Verified bank-uniform for
// strides (row elems) 32/64/128 on b128 reads (all six stepA/stepB patterns).
__device__ __forceinline__ int swz(int T) { return T ^ ((T >> 3) & 7); }

// One factor: stepA + U bounce + stepB + out-RMW. P = p(=q), RR = r(=s).
template<int P, int RR>
__device__ __forceinline__ void factor_step(
        int kf, const unsigned short* __restrict__ Lt, const unsigned short* __restrict__ Rt,
        const unsigned short* Xw, unsigned short* Uw, float* Ow,
        int h, int ln15, int l4) {
    constexpr int MT = P / 16;    // M tiles (iL / jL)
    constexpr int NT = RR / 32;   // N tiles per wave (jR half-split)
    constexpr int KS = RR / 32;   // stepA K-steps (iR)
    constexpr int KS2 = P / 32;   // stepB K-steps (iL)

    // ---------------- stepA: U = X * R ----------------
    f32x4 accu[MT][NT];
#pragma unroll
    for (int mi = 0; mi < MT; ++mi)
#pragma unroll
        for (int ni = 0; ni < NT; ++ni) accu[mi][ni] = (f32x4)(0.0f);

#pragma unroll
    for (int kk = 0; kk < KS; ++kk) {
        short8 bfr[NT];
#pragma unroll
        for (int ni = 0; ni < NT; ++ni) {
            const int jR = h * (RR / 2) + ni * 16 + ln15;
            bfr[ni] = *(const short8*)(Rt + jR * RR + kk * 32 + l4 * 8);
        }
#pragma unroll
        for (int mi = 0; mi < MT; ++mi) {
            const int t = (mi * 16 + ln15) * RR + kk * 32 + l4 * 8;   // X elem idx
            const short8 af = *(const short8*)((const char*)Xw + swz(t >> 3) * 16);
#pragma unroll
            for (int ni = 0; ni < NT; ++ni)
                accu[mi][ni] = __builtin_amdgcn_mfma_f32_16x16x32_bf16(
                    af, bfr[ni], accu[mi][ni], 0, 0, 0);
        }
    }

    // ---------------- U bounce: acc (row=iL, col=jR) -> Uw[jR'][iL] bf16 ----
#pragma unroll
    for (int mi = 0; mi < MT; ++mi)
#pragma unroll
        for (int ni = 0; ni < NT; ++ni) {
            const int jRl = ni * 16 + ln15;
            const int t = jRl * P + mi * 16 + l4 * 4;                 // U elem idx
            uint2 w;
            w.x = f2bf(accu[mi][ni][0]) | (f2bf(accu[mi][ni][1]) << 16);
            w.y = f2bf(accu[mi][ni][2]) | (f2bf(accu[mi][ni][3]) << 16);
            *(uint2*)((char*)Uw + swz(t >> 3) * 16 + (t & 7) * 2) = w;
        }
    PIN();
    asm volatile("s_waitcnt lgkmcnt(0)");   // same-wave U write->read ordering
    PIN();

    // ---------------- stepB: out += Lt * U ----------------
    f32x4 acco[MT][NT];
#pragma unroll
    for (int mi = 0; mi < MT; ++mi)
#pragma unroll
        for (int ni = 0; ni < NT; ++ni) acco[mi][ni] = (f32x4)(0.0f);

#pragma unroll
    for (int kk = 0; kk < KS2; ++kk) {
        short8 ufr[NT];
#pragma unroll
        for (int ni = 0; ni < NT; ++ni) {
            const int t = (ni * 16 + ln15) * P + kk * 32 + l4 * 8;    // U elem idx
            ufr[ni] = *(const short8*)((const char*)Uw + swz(t >> 3) * 16);
        }
#pragma unroll
        for (int mi = 0; mi < MT; ++mi) {
            const int jL = mi * 16 + ln15;
            const short8 af = *(const short8*)(Lt + jL * P + kk * 32 + l4 * 8);
#pragma unroll
            for (int ni = 0; ni < NT; ++ni)
                acco[mi][ni] = __builtin_amdgcn_mfma_f32_16x16x32_bf16(
                    af, ufr[ni], acco[mi][ni], 0, 0, 0);
        }
    }

    // ---------------- out accumulate (padded fp32 LDS row) ----------------
#pragma unroll
    for (int mi = 0; mi < MT; ++mi)
#pragma unroll
        for (int ni = 0; ni < NT; ++ni) {
            const int jbase = (mi * 16 + l4 * 4) * RR + h * (RR / 2) + ni * 16 + ln15;
#pragma unroll
            for (int r = 0; r < 4; ++r) {
                const int j = jbase + r * RR;
                const int o = j + (j >> 5);
                if (kf == 0) Ow[o] = acco[mi][ni][r];
                else         Ow[o] += acco[mi][ni][r];
            }
        }
}

__launch_bounds__(512, 2)
__global__ void kron_fused(const float* __restrict__ x, const unsigned short* __restrict__ F,
                           const float* __restrict__ bias, float* __restrict__ out) {
    __shared__ __align__(16) unsigned short Xs[4][4096];   // 32 KB (per pair, swizzled)
    __shared__ __align__(16) unsigned short Us[8][2048];   // 32 KB (per wave)
    __shared__ __align__(16) float          Os[4][4224];   // 66 KB (per pair, padded)

    const int tid  = threadIdx.x;
    const int wid  = tid >> 6;
    const int lane = tid & 63;
    const int pr   = wid >> 1;      // pair 0..3
    const int h    = wid & 1;       // jR half
    const int ln15 = lane & 15;
    const int l4   = lane >> 4;

    unsigned short* Xw = Xs[pr];
    unsigned short* Uw = Us[wid];
    float*          Ow = Os[pr];

    const unsigned short* Lt0 = F + LT0; const unsigned short* Rt0 = F + RT0;
    const unsigned short* Lt1 = F + LT1; const unsigned short* Rt1 = F + RT1;
    const unsigned short* Lt2 = F + LT2; const unsigned short* Rt2 = F + RT2;

    for (int it = 0; it < 16; ++it) {
        const int row = blockIdx.x * 64 + pr * 16 + it;

        // ---- load row half -> bf16 -> swizzled LDS ----
        const float* xr = x + (size_t)row * 4096 + h * 2048;
#pragma unroll
        for (int i = 0; i < 8; ++i) {
            const f32x4 v = *(const f32x4*)(xr + i * 256 + lane * 4);
            uint2 w;
            w.x = f2bf(v[0]) | (f2bf(v[1]) << 16);
            w.y = f2bf(v[2]) | (f2bf(v[3]) << 16);
            const int t = h * 2048 + i * 256 + lane * 4;
            *(uint2*)((char*)Xw + swz(t >> 3) * 16 + (t & 7) * 2) = w;
        }
        __syncthreads();

        // ---- three factors ----
        factor_step< 64,  64>(0, Lt0, Rt0, Xw, Uw, Ow, h, ln15, l4);
        factor_step< 32, 128>(1, Lt1, Rt1, Xw, Uw, Ow, h, ln15, l4);
        factor_step<128,  32>(2, Lt2, Rt2, Xw, Uw, Ow, h, ln15, l4);
        __syncthreads();

        // ---- flush: Os (+bias) -> out, coalesced 1KB/instr ----
#pragma unroll
        for (int i = 0; i < 8; ++i) {
            const int j = (h * 8 + i) * 256 + lane * 4;
            const int o = j + (j >> 5);
            f32x4 v = *(const f32x4*)&Ow[o];
            const f32x4 b = *(const f32x4*)&bias[j];
            v[0] += b[0]; v[1] += b[1]; v[2] += b[2]; v[3] += b[3];
            *(f32x4*)&out[(size_t)row * 4096 + j] = v;
        }
        __syncthreads();
    }
}

// ---------------------------------------------------------------------------
extern "C" void kernel_launch(void* const* d_in, const int* in_sizes, int n_in,
                              void* d_out, int out_size, void* d_ws, size_t ws_size,
                              hipStream_t stream) {
    const float* x    = (const float*)d_in[0];
    const float* L0   = (const float*)d_in[1];
    const float* R0   = (const float*)d_in[2];
    const float* L1   = (const float*)d_in[3];
    const float* R1   = (const float*)d_in[4];
    const float* L2   = (const float*)d_in[5];
    const float* R2   = (const float*)d_in[6];
    const float* bias = (const float*)d_in[7];
    float* out = (float*)d_out;

    unsigned short* F = (unsigned short*)d_ws;   // 86 KB of transposed bf16 factors

    prep<<<dim3(168), dim3(256), 0, stream>>>(L0, R0, L1, R1, L2, R2, F);
    kron_fused<<<dim3(256), dim3(512), 0, stream>>>(x, F, bias, out);
}